// Round 4
// baseline (1494.778 us; speedup 1.0000x reference)
//
#include <hip/hip_runtime.h>
#include <hip/hip_bf16.h>
#include <cstdint>

typedef __attribute__((ext_vector_type(8))) short bf16x8;
typedef __attribute__((ext_vector_type(4))) float f32x4;

#define DEV __device__ __forceinline__

DEV float b2f(unsigned short u) {
  union { unsigned int i; float f; } v; v.i = ((unsigned int)u) << 16; return v.f;
}
DEV unsigned short f2b(float f) {
  __hip_bfloat16 h = __float2bfloat16(f);
  return *reinterpret_cast<unsigned short*>(&h);
}
DEV float gelu_f(float x) { return 0.5f * x * (1.0f + erff(x * 0.70710678118654752f)); }

// ---- dtype canonicalization ------------------------------------------------
// Inputs may be fp32 or bf16 (harness-dependent). Sniff from lnf_g (all 1.0):
// fp32 first u32 = 0x3F800000; bf16 pair = 0x3F803F80.
__global__ void probe_kernel(const unsigned int* __restrict__ g, int* __restrict__ flag) {
  if (threadIdx.x == 0 && blockIdx.x == 0) *flag = (*g == 0x3F800000u) ? 1 : 0;
}

struct CvtArgs {
  const void* src[42];
  unsigned int off[43];  // element prefix offsets
};

__global__ __launch_bounds__(256) void cvt_kernel(CvtArgs a, int n_t, unsigned int total,
                                                  const int* __restrict__ flag,
                                                  unsigned short* __restrict__ dst) {
  unsigned int i = blockIdx.x * 256u + threadIdx.x;
  if (i >= total) return;
  int t = 0;
  while (t + 1 < n_t && i >= a.off[t + 1]) t++;
  unsigned int j = i - a.off[t];
  unsigned short v;
  if (*flag) v = f2b(((const float*)a.src[t])[j]);
  else       v = ((const unsigned short*)a.src[t])[j];
  dst[i] = v;
}

// ---- GEMM ------------------------------------------------------------------
// C = epi(A[M,K] @ W[N,K]^T + bias), A/W bf16 row-major (K contiguous).
// mode 0: bf16 out = x + bias
// mode 1: bf16 out = gelu(x + bias)
// mode 2: f32  out = x + bias + pos[(m&511)*512+n]
// mode 3: f32  out[m*N+n] += x + bias   (residual accumulate)
__global__ __launch_bounds__(256) void gemm_bt(
    const unsigned short* __restrict__ A, const unsigned short* __restrict__ W,
    const unsigned short* __restrict__ bias,
    unsigned short* __restrict__ outB, float* __restrict__ outF,
    const unsigned short* __restrict__ pos,
    int N, int K, int mode)
{
  __shared__ __align__(16) unsigned short As[128 * 32];
  __shared__ __align__(16) unsigned short Bs[128 * 32];
  int t = threadIdx.x;
  int l = t & 63;
  int w = t >> 6;
  int wr = w >> 1, wc = w & 1;
  int col = l & 15, quad = l >> 4;
  int m0 = blockIdx.x * 128;
  int n0 = blockIdx.y * 128;

  f32x4 acc[4][4];
#pragma unroll
  for (int i = 0; i < 4; i++)
#pragma unroll
    for (int j = 0; j < 4; j++) acc[i][j] = (f32x4){0.f, 0.f, 0.f, 0.f};

  int g1i = t, g2i = t + 256;
  const unsigned short* a1 = A + (size_t)(m0 + (g1i >> 2)) * K + (g1i & 3) * 8;
  const unsigned short* a2 = A + (size_t)(m0 + (g2i >> 2)) * K + (g2i & 3) * 8;
  const unsigned short* b1 = W + (size_t)(n0 + (g1i >> 2)) * K + (g1i & 3) * 8;
  const unsigned short* b2 = W + (size_t)(n0 + (g2i >> 2)) * K + (g2i & 3) * 8;
  unsigned short* la1 = &As[g1i * 8];
  unsigned short* la2 = &As[g2i * 8];
  unsigned short* lb1 = &Bs[g1i * 8];
  unsigned short* lb2 = &Bs[g2i * 8];

  for (int kt = 0; kt < K; kt += 32) {
    float4 ra1 = *(const float4*)(a1 + kt);
    float4 ra2 = *(const float4*)(a2 + kt);
    float4 rb1 = *(const float4*)(b1 + kt);
    float4 rb2 = *(const float4*)(b2 + kt);
    __syncthreads();
    *(float4*)la1 = ra1;
    *(float4*)la2 = ra2;
    *(float4*)lb1 = rb1;
    *(float4*)lb2 = rb2;
    __syncthreads();

    bf16x8 af[4], bfv[4];
#pragma unroll
    for (int mi = 0; mi < 4; mi++)
      af[mi] = *(const bf16x8*)&As[(wr * 64 + mi * 16 + col) * 32 + quad * 8];
#pragma unroll
    for (int ni = 0; ni < 4; ni++)
      bfv[ni] = *(const bf16x8*)&Bs[(wc * 64 + ni * 16 + col) * 32 + quad * 8];
#pragma unroll
    for (int mi = 0; mi < 4; mi++)
#pragma unroll
      for (int ni = 0; ni < 4; ni++)
        acc[mi][ni] = __builtin_amdgcn_mfma_f32_16x16x32_bf16(af[mi], bfv[ni], acc[mi][ni], 0, 0, 0);
  }

  int mBase = m0 + wr * 64, nBase = n0 + wc * 64;
#pragma unroll
  for (int mi = 0; mi < 4; mi++) {
#pragma unroll
    for (int ni = 0; ni < 4; ni++) {
      int n = nBase + ni * 16 + col;
      float bv = b2f(bias[n]);
      f32x4 v = acc[mi][ni];
#pragma unroll
      for (int r = 0; r < 4; r++) {
        int m = mBase + mi * 16 + quad * 4 + r;
        float x = v[r] + bv;
        if (mode == 0) {
          outB[(size_t)m * N + n] = f2b(x);
        } else if (mode == 1) {
          outB[(size_t)m * N + n] = f2b(gelu_f(x));
        } else if (mode == 2) {
          outF[(size_t)m * N + n] = x + b2f(pos[(m & 511) * 512 + n]);
        } else {
          outF[(size_t)m * N + n] += x;
        }
      }
    }
  }
}

// dst[m][ci*3+tap] = src[m+tap-1][ci] (zero-padded along s within each batch)
__global__ void im2col3_kernel(const unsigned short* __restrict__ src,
                               unsigned short* __restrict__ dst, int C)
{
  int m = blockIdx.x;
  int k = blockIdx.y * blockDim.x + threadIdx.x;  // [0, 3C)
  int ci = k / 3;
  int tap = k - ci * 3;
  int s = m & 511;
  int sp = s + tap - 1;
  unsigned short val = 0;
  if (sp >= 0 && sp < 512) val = src[(size_t)(m + tap - 1) * C + ci];
  dst[(size_t)m * (3 * C) + k] = val;
}

// LayerNorm over D=512; one wave per row; z fp32 -> bf16 out.
__global__ __launch_bounds__(256) void ln_kernel(
    const float* __restrict__ z, const unsigned short* __restrict__ gam,
    const unsigned short* __restrict__ bet, unsigned short* __restrict__ out)
{
  int w = threadIdx.x >> 6, l = threadIdx.x & 63;
  int row = blockIdx.x * 4 + w;
  const float* zr = z + (size_t)row * 512;
  float4 v0 = *(const float4*)(zr + l * 8);
  float4 v1 = *(const float4*)(zr + l * 8 + 4);
  float x[8] = {v0.x, v0.y, v0.z, v0.w, v1.x, v1.y, v1.z, v1.w};
#pragma unroll
  for (int i = 0; i < 8; i++) x[i] = fmaxf(fminf(x[i], 1e18f), -1e18f);
  float s = 0.f;
#pragma unroll
  for (int i = 0; i < 8; i++) s += x[i];
#pragma unroll
  for (int mm = 1; mm < 64; mm <<= 1) s += __shfl_xor(s, mm, 64);
  float mu = s * (1.0f / 512.0f);
  float vs = 0.f;
#pragma unroll
  for (int i = 0; i < 8; i++) { float d = x[i] - mu; vs += d * d; }
#pragma unroll
  for (int mm = 1; mm < 64; mm <<= 1) vs += __shfl_xor(vs, mm, 64);
  float rs = rsqrtf(vs * (1.0f / 512.0f) + 1e-5f);
  struct alignas(16) U8 { unsigned short u[8]; };
  U8 gg = *(const U8*)(gam + l * 8);
  U8 bb = *(const U8*)(bet + l * 8);
  U8 o;
#pragma unroll
  for (int i = 0; i < 8; i++) o.u[i] = f2b((x[i] - mu) * rs * b2f(gg.u[i]) + b2f(bb.u[i]));
  *(U8*)(out + (size_t)row * 512 + l * 8) = o;
}

// Final LN on last token only: 16 rows (b, s=511) -> feat[b][512]
__global__ __launch_bounds__(256) void lnf_kernel(
    const float* __restrict__ z, const unsigned short* __restrict__ gam,
    const unsigned short* __restrict__ bet, unsigned short* __restrict__ feat)
{
  int w = threadIdx.x >> 6, l = threadIdx.x & 63;
  int b = blockIdx.x * 4 + w;
  const float* zr = z + ((size_t)b * 512 + 511) * 512;
  float4 v0 = *(const float4*)(zr + l * 8);
  float4 v1 = *(const float4*)(zr + l * 8 + 4);
  float x[8] = {v0.x, v0.y, v0.z, v0.w, v1.x, v1.y, v1.z, v1.w};
#pragma unroll
  for (int i = 0; i < 8; i++) x[i] = fmaxf(fminf(x[i], 1e18f), -1e18f);
  float s = 0.f;
#pragma unroll
  for (int i = 0; i < 8; i++) s += x[i];
#pragma unroll
  for (int mm = 1; mm < 64; mm <<= 1) s += __shfl_xor(s, mm, 64);
  float mu = s * (1.0f / 512.0f);
  float vs = 0.f;
#pragma unroll
  for (int i = 0; i < 8; i++) { float d = x[i] - mu; vs += d * d; }
#pragma unroll
  for (int mm = 1; mm < 64; mm <<= 1) vs += __shfl_xor(vs, mm, 64);
  float rs = rsqrtf(vs * (1.0f / 512.0f) + 1e-5f);
  struct alignas(16) U8 { unsigned short u[8]; };
  U8 gg = *(const U8*)(gam + l * 8);
  U8 bb = *(const U8*)(bet + l * 8);
  U8 o;
#pragma unroll
  for (int i = 0; i < 8; i++) o.u[i] = f2b((x[i] - mu) * rs * b2f(gg.u[i]) + b2f(bb.u[i]));
  *(U8*)(feat + (size_t)b * 512 + l * 8) = o;
}

// V (b,s,h*64+e) -> VT (b,h,e,s)
__global__ __launch_bounds__(256) void vtrans_kernel(const unsigned short* __restrict__ V,
                                                     unsigned short* __restrict__ VT)
{
  __shared__ unsigned short tile[64][72];
  int s0 = blockIdx.x * 64;
  int bh = blockIdx.y; int b = bh >> 3, h = bh & 7;
  int t = threadIdx.x;
  int rs = t >> 2, c = (t & 3) * 16;
  const unsigned short* src = V + ((size_t)(b * 512 + s0 + rs) * 512 + h * 64 + c);
  *(float4*)&tile[rs][c] = *(const float4*)src;
  *(float4*)&tile[rs][c + 8] = *(const float4*)(src + 8);
  __syncthreads();
  unsigned short* dst = VT + ((size_t)(bh * 64 + rs) * 512 + s0 + c);
  union { unsigned short u[16]; float4 f[2]; } ot;
#pragma unroll
  for (int i = 0; i < 16; i++) ot.u[i] = tile[c + i][rs];
  *(float4*)dst = ot.f[0];
  *(float4*)(dst + 8) = ot.f[1];
}

// Fused masked attention, flash-style. Grid (S/64, B*H).
__global__ __launch_bounds__(256) void attn_kernel(
    const unsigned short* __restrict__ Q, const unsigned short* __restrict__ Kg,
    const unsigned short* __restrict__ VT, unsigned short* __restrict__ O)
{
  __shared__ __align__(16) unsigned short Qs[64 * 64];
  __shared__ __align__(16) unsigned short Ks[64 * 64];
  __shared__ __align__(16) unsigned short Vts[64 * 64];
  __shared__ __align__(16) unsigned short Ps[64 * 64];
  const float NEG = -1e30f;
  int bh = blockIdx.y; int b = bh >> 3, h = bh & 7;
  int i0 = blockIdx.x * 64;
  int t = threadIdx.x, w = t >> 6, l = t & 63;
  int col = l & 15, quad = l >> 4;
  int dil = 1 << (h < 4 ? h : 4);
  int per_m1 = 2 * dil - 1;

  {
    int row = t >> 2, c = (t & 3) * 16;
    const unsigned short* src = Q + ((size_t)(b * 512 + i0 + row) * 512 + h * 64 + c);
    *(float4*)&Qs[row * 64 + c] = *(const float4*)src;
    *(float4*)&Qs[row * 64 + c + 8] = *(const float4*)(src + 8);
  }
  __syncthreads();

  bf16x8 qa[2];
#pragma unroll
  for (int kk = 0; kk < 2; kk++)
    qa[kk] = *(const bf16x8*)&Qs[(w * 16 + col) * 64 + kk * 32 + quad * 8];

  f32x4 acc_o[4];
#pragma unroll
  for (int i = 0; i < 4; i++) acc_o[i] = (f32x4){0.f, 0.f, 0.f, 0.f};
  float m_run[4], l_run[4];
#pragma unroll
  for (int r = 0; r < 4; r++) { m_run[r] = NEG; l_run[r] = 0.f; }

  for (int jt = 0; jt < 8; jt++) {
    int j0 = jt * 64;
    {
      int row = t >> 2, c = (t & 3) * 16;
      const unsigned short* ks = Kg + ((size_t)(b * 512 + j0 + row) * 512 + h * 64 + c);
      *(float4*)&Ks[row * 64 + c] = *(const float4*)ks;
      *(float4*)&Ks[row * 64 + c + 8] = *(const float4*)(ks + 8);
      const unsigned short* vs = VT + ((size_t)(bh * 64 + row) * 512 + j0 + c);
      *(float4*)&Vts[row * 64 + c] = *(const float4*)vs;
      *(float4*)&Vts[row * 64 + c + 8] = *(const float4*)(vs + 8);
    }
    __syncthreads();

    f32x4 sa[4];
#pragma unroll
    for (int ni = 0; ni < 4; ni++) {
      f32x4 s = (f32x4){0.f, 0.f, 0.f, 0.f};
#pragma unroll
      for (int kk = 0; kk < 2; kk++) {
        bf16x8 kb = *(const bf16x8*)&Ks[(ni * 16 + col) * 64 + kk * 32 + quad * 8];
        s = __builtin_amdgcn_mfma_f32_16x16x32_bf16(qa[kk], kb, s, 0, 0, 0);
      }
      sa[ni] = s;
    }

    float pv[4][4];
    float alpha_r[4];
#pragma unroll
    for (int r = 0; r < 4; r++) {
      int ig = i0 + w * 16 + quad * 4 + r;
      float sv[4]; float mx = NEG;
#pragma unroll
      for (int ni = 0; ni < 4; ni++) {
        int jg = j0 + ni * 16 + col;
        int d = ig - jg; d = d < 0 ? -d : d;
        bool keep = (d <= dil) || ((d & per_m1) == 0);
        float s = keep ? fminf(sa[ni][r] * 0.125f, 80.0f) : NEG;
        sv[ni] = s; mx = fmaxf(mx, s);
      }
#pragma unroll
      for (int mm = 1; mm < 16; mm <<= 1) mx = fmaxf(mx, __shfl_xor(mx, mm, 64));
      float mN = fmaxf(m_run[r], mx);
      float a = __expf(m_run[r] - mN);
      float rsum = 0.f;
#pragma unroll
      for (int ni = 0; ni < 4; ni++) { float p = __expf(sv[ni] - mN); pv[ni][r] = p; rsum += p; }
#pragma unroll
      for (int mm = 1; mm < 16; mm <<= 1) rsum += __shfl_xor(rsum, mm, 64);
      l_run[r] = l_run[r] * a + rsum;
      m_run[r] = mN;
      alpha_r[r] = a;
    }
#pragma unroll
    for (int ne = 0; ne < 4; ne++)
#pragma unroll
      for (int r = 0; r < 4; r++) acc_o[ne][r] *= alpha_r[r];
#pragma unroll
    for (int ni = 0; ni < 4; ni++)
#pragma unroll
      for (int r = 0; r < 4; r++)
        Ps[(w * 16 + quad * 4 + r) * 64 + ni * 16 + col] = f2b(pv[ni][r]);
    __syncthreads();

    bf16x8 pa[2];
#pragma unroll
    for (int kk = 0; kk < 2; kk++)
      pa[kk] = *(const bf16x8*)&Ps[(w * 16 + col) * 64 + kk * 32 + quad * 8];
#pragma unroll
    for (int ne = 0; ne < 4; ne++) {
#pragma unroll
      for (int kk = 0; kk < 2; kk++) {
        bf16x8 vb = *(const bf16x8*)&Vts[(ne * 16 + col) * 64 + kk * 32 + quad * 8];
        acc_o[ne] = __builtin_amdgcn_mfma_f32_16x16x32_bf16(pa[kk], vb, acc_o[ne], 0, 0, 0);
      }
    }
    __syncthreads();
  }

  float inv[4];
#pragma unroll
  for (int r = 0; r < 4; r++) inv[r] = 1.0f / fmaxf(l_run[r], 1e-20f);
#pragma unroll
  for (int ne = 0; ne < 4; ne++)
#pragma unroll
    for (int r = 0; r < 4; r++) {
      float o = acc_o[ne][r] * inv[r];
      O[((size_t)(b * 512 + i0 + w * 16 + quad * 4 + r)) * 512 + h * 64 + ne * 16 + col] = f2b(o);
    }
}

// Both MLP heads for one sample per block; output dtype per flag.
__global__ __launch_bounds__(256) void heads_kernel(
    const unsigned short* __restrict__ feat,
    const unsigned short* __restrict__ a1w, const unsigned short* __restrict__ a1b,
    const unsigned short* __restrict__ a2w, const unsigned short* __restrict__ a2b,
    const unsigned short* __restrict__ a3w, const unsigned short* __restrict__ a3b,
    const unsigned short* __restrict__ a4w, const unsigned short* __restrict__ a4b,
    const unsigned short* __restrict__ c1w, const unsigned short* __restrict__ c1b,
    const unsigned short* __restrict__ c2w, const unsigned short* __restrict__ c2b,
    const unsigned short* __restrict__ c3w, const unsigned short* __restrict__ c3b,
    const unsigned short* __restrict__ c4w, const unsigned short* __restrict__ c4b,
    const int* __restrict__ flag, void* __restrict__ outv)
{
  __shared__ float f[512];
  __shared__ float g1[256];
  __shared__ float g2[512];
  __shared__ float g3[128];
  int b = blockIdx.x, t = threadIdx.x;
  f[t] = b2f(feat[b * 512 + t]);
  f[t + 256] = b2f(feat[b * 512 + 256 + t]);
  __syncthreads();
  {
    const unsigned short* wrow; float bias;
    if (t < 128) { wrow = a1w + (size_t)t * 512; bias = b2f(a1b[t]); }
    else { wrow = c1w + (size_t)(t - 128) * 512; bias = b2f(c1b[t - 128]); }
    float s = bias;
    for (int k = 0; k < 512; k++) s += b2f(wrow[k]) * f[k];
    g1[t] = gelu_f(s);
  }
  __syncthreads();
  {
    float s1 = b2f(a2b[t]);
    for (int k = 0; k < 128; k++) s1 += b2f(a2w[t * 128 + k]) * g1[k];
    float s2 = b2f(c2b[t]);
    for (int k = 0; k < 128; k++) s2 += b2f(c2w[t * 128 + k]) * g1[128 + k];
    g2[t] = gelu_f(s1);
    g2[256 + t] = gelu_f(s2);
  }
  __syncthreads();
  if (t < 57) {
    float s = b2f(a3b[t]);
    for (int k = 0; k < 256; k++) s += b2f(a3w[t * 256 + k]) * g2[k];
    g3[t] = gelu_f(s);
  } else if (t >= 64 && t < 121) {
    int u = t - 64;
    float s = b2f(c3b[u]);
    for (int k = 0; k < 256; k++) s += b2f(c3w[u * 256 + k]) * g2[256 + k];
    g3[64 + u] = gelu_f(s);
  }
  __syncthreads();
  int fp32out = *flag;
  if (t < 3) {
    float s = b2f(a4b[t]);
    for (int k = 0; k < 57; k++) s += b2f(a4w[t * 57 + k]) * g3[k];
    if (fp32out) ((float*)outv)[b * 3 + t] = s;
    else ((unsigned short*)outv)[b * 3 + t] = f2b(s);
  } else if (t == 4) {
    float s = b2f(c4b[0]);
    for (int k = 0; k < 57; k++) s += b2f(c4w[k]) * g3[64 + k];
    if (fp32out) ((float*)outv)[48 + b] = s;
    else ((unsigned short*)outv)[48 + b] = f2b(s);
  }
}

extern "C" void kernel_launch(void* const* d_in, const int* in_sizes, int n_in,
                              void* d_out, int out_size, void* d_ws, size_t ws_size,
                              hipStream_t stream)
{
  typedef unsigned short u16;

  // ws layout: z [0,16M) | R [16M,48M) | bufH [48M,56M) | pool [56M, ~85M) | flag @88M
  char* ws = (char*)d_ws;
  float* z    = (float*)ws;
  u16* R      = (u16*)(ws + (16u << 20));
  u16* bufQ   = R;
  u16* bufK   = (u16*)(ws + (24u << 20));
  u16* bufV   = (u16*)(ws + (32u << 20));
  u16* bufVT  = (u16*)(ws + (40u << 20));
  u16* bufO   = bufV;
  u16* bufH   = (u16*)(ws + (48u << 20));
  u16* feat   = R;
  u16* pool   = (u16*)(ws + (56u << 20));
  int* flag   = (int*)(ws + (88u << 20));

  // canonicalize inputs -> bf16 pool
  CvtArgs args;
  unsigned int off = 0;
  int nt = n_in < 42 ? n_in : 42;
  for (int i = 0; i < nt; i++) { args.src[i] = d_in[i]; args.off[i] = off; off += (unsigned int)in_sizes[i]; }
  args.off[nt] = off;
  for (int i = nt; i < 42; i++) { args.src[i] = d_in[nt - 1]; if (i < 42) args.off[i + 1] = off; }
  unsigned int total = off;

  probe_kernel<<<1, 64, 0, stream>>>((const unsigned int*)d_in[24], flag);
  cvt_kernel<<<(total + 255) / 256, 256, 0, stream>>>(args, nt, total, flag, pool);

  // canonical bf16 pointers
  const u16* P[42];
  for (int i = 0; i < nt; i++) P[i] = pool + args.off[i];
  const u16* x       = P[0];
  const u16* conv1_w = P[1];  const u16* conv1_b = P[2];
  const u16* conv2_w = P[3];  const u16* conv2_b = P[4];
  const u16* emb_w   = P[5];  const u16* emb_b   = P[6];
  const u16* pos     = P[7];
  const u16* Wq      = P[8];  const u16* bq      = P[9];
  const u16* Wk      = P[10]; const u16* bk      = P[11];
  const u16* Wv      = P[12]; const u16* bv      = P[13];
  const u16* Wo      = P[14]; const u16* bo      = P[15];
  const u16* ln1_g   = P[16]; const u16* ln1_b   = P[17];
  const u16* ln2_g   = P[18]; const u16* ln2_b   = P[19];
  const u16* W1      = P[20]; const u16* b1      = P[21];
  const u16* W2      = P[22]; const u16* b2      = P[23];
  const u16* lnf_g   = P[24]; const u16* lnf_b   = P[25];

  // conv front-end as im2col + GEMM(+GELU)
  im2col3_kernel<<<dim3(8192, 1), 192, 0, stream>>>(x, R, 64);
  gemm_bt<<<dim3(64, 2), 256, 0, stream>>>(R, conv1_w, conv1_b, bufH, nullptr, nullptr, 256, 192, 1);
  im2col3_kernel<<<dim3(8192, 3), 256, 0, stream>>>(bufH, R, 256);
  gemm_bt<<<dim3(64, 4), 256, 0, stream>>>(R, conv2_w, conv2_b, bufH, nullptr, nullptr, 512, 768, 1);
  gemm_bt<<<dim3(64, 4), 256, 0, stream>>>(bufH, emb_w, emb_b, nullptr, z, pos, 512, 512, 2);

  for (int l = 0; l < 4; l++) {
    ln_kernel<<<2048, 256, 0, stream>>>(z, ln1_g + l * 512, ln1_b + l * 512, bufH);
    gemm_bt<<<dim3(64, 4), 256, 0, stream>>>(bufH, Wq + (size_t)l * 262144, bq + l * 512, bufQ, nullptr, nullptr, 512, 512, 0);
    gemm_bt<<<dim3(64, 4), 256, 0, stream>>>(bufH, Wk + (size_t)l * 262144, bk + l * 512, bufK, nullptr, nullptr, 512, 512, 0);
    gemm_bt<<<dim3(64, 4), 256, 0, stream>>>(bufH, Wv + (size_t)l * 262144, bv + l * 512, bufV, nullptr, nullptr, 512, 512, 0);
    vtrans_kernel<<<dim3(8, 128), 256, 0, stream>>>(bufV, bufVT);
    attn_kernel<<<dim3(8, 128), 256, 0, stream>>>(bufQ, bufK, bufVT, bufO);
    gemm_bt<<<dim3(64, 4), 256, 0, stream>>>(bufO, Wo + (size_t)l * 262144, bo + l * 512, nullptr, z, nullptr, 512, 512, 3);
    ln_kernel<<<2048, 256, 0, stream>>>(z, ln2_g + l * 512, ln2_b + l * 512, bufH);
    gemm_bt<<<dim3(64, 16), 256, 0, stream>>>(bufH, W1 + (size_t)l * 1048576, b1 + l * 2048, R, nullptr, nullptr, 2048, 512, 1);
    gemm_bt<<<dim3(64, 4), 256, 0, stream>>>(R, W2 + (size_t)l * 1048576, b2 + l * 512, nullptr, z, nullptr, 512, 2048, 3);
  }

  lnf_kernel<<<4, 256, 0, stream>>>(z, lnf_g, lnf_b, feat);
  heads_kernel<<<16, 256, 0, stream>>>(feat,
      P[26], P[27], P[28], P[29], P[30], P[31], P[32], P[33],
      P[34], P[35], P[36], P[37], P[38], P[39], P[40], P[41],
      flag, d_out);
}

// Round 5
// 1274.868 us; speedup vs baseline: 1.1725x; 1.1725x over previous
//
#include <hip/hip_runtime.h>
#include <hip/hip_bf16.h>
#include <cstdint>

typedef __attribute__((ext_vector_type(8))) short bf16x8;
typedef __attribute__((ext_vector_type(4))) float f32x4;

#define DEV __device__ __forceinline__

DEV float b2f(unsigned short u) {
  union { unsigned int i; float f; } v; v.i = ((unsigned int)u) << 16; return v.f;
}
DEV unsigned short f2b(float f) {
  __hip_bfloat16 h = __float2bfloat16(f);
  return *reinterpret_cast<unsigned short*>(&h);
}
DEV float gelu_f(float x) { return 0.5f * x * (1.0f + erff(x * 0.70710678118654752f)); }

DEV void async_cp16(const unsigned short* g, unsigned short* l) {
  __builtin_amdgcn_global_load_lds(
      (const __attribute__((address_space(1))) void*)g,
      (__attribute__((address_space(3))) void*)l, 16, 0, 0);
}

// ---- dtype canonicalization ------------------------------------------------
__global__ void probe_kernel(const unsigned int* __restrict__ g, int* __restrict__ flag) {
  if (threadIdx.x == 0 && blockIdx.x == 0) *flag = (*g == 0x3F800000u) ? 1 : 0;
}

struct CvtArgs {
  const void* src[42];
  unsigned int off[43];  // element prefix offsets
};

struct alignas(16) U8v { unsigned short u[8]; };

// 8 elements/thread, vector path when the run stays in one segment & aligned.
__global__ __launch_bounds__(256) void cvt_kernel(CvtArgs a, int n_t, unsigned int total,
                                                  const int* __restrict__ flag,
                                                  unsigned short* __restrict__ dst) {
  unsigned int i8 = (blockIdx.x * 256u + threadIdx.x) * 8u;
  if (i8 >= total) return;
  int t = 0;
  while (t + 1 < n_t && i8 >= a.off[t + 1]) t++;
  unsigned int j = i8 - a.off[t];
  bool in_seg = (i8 + 8 <= a.off[t + 1]) && (i8 + 8 <= total);
  int fp32 = *flag;
  if (fp32) {
    if (in_seg && ((j & 3) == 0)) {
      const float* s = (const float*)a.src[t] + j;
      float4 v0 = *(const float4*)s;
      float4 v1 = *(const float4*)(s + 4);
      U8v o;
      o.u[0] = f2b(v0.x); o.u[1] = f2b(v0.y); o.u[2] = f2b(v0.z); o.u[3] = f2b(v0.w);
      o.u[4] = f2b(v1.x); o.u[5] = f2b(v1.y); o.u[6] = f2b(v1.z); o.u[7] = f2b(v1.w);
      *(U8v*)(dst + i8) = o;
    } else {
      for (int k = 0; k < 8; k++) {
        unsigned int i = i8 + k;
        if (i >= total) break;
        int tt = t;
        while (tt + 1 < n_t && i >= a.off[tt + 1]) tt++;
        dst[i] = f2b(((const float*)a.src[tt])[i - a.off[tt]]);
      }
    }
  } else {
    if (in_seg && ((j & 7) == 0)) {
      *(U8v*)(dst + i8) = *(const U8v*)((const unsigned short*)a.src[t] + j);
    } else {
      for (int k = 0; k < 8; k++) {
        unsigned int i = i8 + k;
        if (i >= total) break;
        int tt = t;
        while (tt + 1 < n_t && i >= a.off[tt + 1]) tt++;
        dst[i] = ((const unsigned short*)a.src[tt])[i - a.off[tt]];
      }
    }
  }
}

// ---- GEMM (async global_load_lds staging, m97 structure) --------------------
// C = epi(A[M,K] @ W[N,K]^T + bias)
// mode 0: bf16 out = x + bias
// mode 1: bf16 out = gelu(x + bias)
// mode 2: f32  out = x + bias + pos[(m&511)*512+n]
// mode 3: f32  out[m*N+n] += x + bias   (residual accumulate)
__global__ __launch_bounds__(256) void gemm_bt(
    const unsigned short* __restrict__ A, const unsigned short* __restrict__ W,
    const unsigned short* __restrict__ bias,
    unsigned short* __restrict__ outB, float* __restrict__ outF,
    const unsigned short* __restrict__ pos,
    int N, int K, int mode)
{
  __shared__ __align__(16) unsigned short As[128 * 32];
  __shared__ __align__(16) unsigned short Bs[128 * 32];
  int t = threadIdx.x;
  int l = t & 63;
  int w = t >> 6;
  int wr = w >> 1, wc = w & 1;
  int col = l & 15, quad = l >> 4;
  int m0 = blockIdx.x * 128;
  int n0 = blockIdx.y * 128;

  f32x4 acc[4][4];
#pragma unroll
  for (int i = 0; i < 4; i++)
#pragma unroll
    for (int j = 0; j < 4; j++) acc[i][j] = (f32x4){0.f, 0.f, 0.f, 0.f};

  int g1i = t, g2i = t + 256;
  const unsigned short* a1 = A + (size_t)(m0 + (g1i >> 2)) * K + (g1i & 3) * 8;
  const unsigned short* a2 = A + (size_t)(m0 + (g2i >> 2)) * K + (g2i & 3) * 8;
  const unsigned short* b1 = W + (size_t)(n0 + (g1i >> 2)) * K + (g1i & 3) * 8;
  const unsigned short* b2 = W + (size_t)(n0 + (g2i >> 2)) * K + (g2i & 3) * 8;
  unsigned short* la1 = &As[g1i * 8];
  unsigned short* la2 = &As[g2i * 8];
  unsigned short* lb1 = &Bs[g1i * 8];
  unsigned short* lb2 = &Bs[g2i * 8];

  for (int kt = 0; kt < K; kt += 32) {
    async_cp16(a1 + kt, la1);
    async_cp16(a2 + kt, la2);
    async_cp16(b1 + kt, lb1);
    async_cp16(b2 + kt, lb2);
    __syncthreads();
    bf16x8 af[4], bfv[4];
#pragma unroll
    for (int mi = 0; mi < 4; mi++)
      af[mi] = *(const bf16x8*)&As[(wr * 64 + mi * 16 + col) * 32 + quad * 8];
#pragma unroll
    for (int ni = 0; ni < 4; ni++)
      bfv[ni] = *(const bf16x8*)&Bs[(wc * 64 + ni * 16 + col) * 32 + quad * 8];
#pragma unroll
    for (int mi = 0; mi < 4; mi++)
#pragma unroll
      for (int ni = 0; ni < 4; ni++)
        acc[mi][ni] = __builtin_amdgcn_mfma_f32_16x16x32_bf16(af[mi], bfv[ni], acc[mi][ni], 0, 0, 0);
    __syncthreads();
  }

  int mBase = m0 + wr * 64, nBase = n0 + wc * 64;
#pragma unroll
  for (int mi = 0; mi < 4; mi++) {
#pragma unroll
    for (int ni = 0; ni < 4; ni++) {
      int n = nBase + ni * 16 + col;
      float bv = b2f(bias[n]);
      f32x4 v = acc[mi][ni];
#pragma unroll
      for (int r = 0; r < 4; r++) {
        int m = mBase + mi * 16 + quad * 4 + r;
        float x = v[r] + bv;
        if (mode == 0) {
          outB[(size_t)m * N + n] = f2b(x);
        } else if (mode == 1) {
          outB[(size_t)m * N + n] = f2b(gelu_f(x));
        } else if (mode == 2) {
          outF[(size_t)m * N + n] = x + b2f(pos[(m & 511) * 512 + n]);
        } else {
          outF[(size_t)m * N + n] += x;
        }
      }
    }
  }
}

// Fused Q,K,V projection: one dispatch, N=1536 logical (3x512), 768 blocks.
// blockIdx.y in [0,12): sel = y>>2 chooses {Wq,Wk,Wv}; n0 = (y&3)*128.
// Output regions Q,K,V are contiguous: outBase + sel*outStride.
__global__ __launch_bounds__(256) void gemm_qkv(
    const unsigned short* __restrict__ A,
    const unsigned short* __restrict__ Wq, const unsigned short* __restrict__ Wk,
    const unsigned short* __restrict__ Wv,
    const unsigned short* __restrict__ bq, const unsigned short* __restrict__ bk,
    const unsigned short* __restrict__ bv,
    unsigned short* __restrict__ outBase, size_t outStride, int K)
{
  __shared__ __align__(16) unsigned short As[128 * 32];
  __shared__ __align__(16) unsigned short Bs[128 * 32];
  int t = threadIdx.x;
  int l = t & 63;
  int w = t >> 6;
  int wr = w >> 1, wc = w & 1;
  int col = l & 15, quad = l >> 4;
  int m0 = blockIdx.x * 128;
  int sel = blockIdx.y >> 2;
  int n0 = (blockIdx.y & 3) * 128;
  const unsigned short* W = sel == 0 ? Wq : (sel == 1 ? Wk : Wv);
  const unsigned short* bias = sel == 0 ? bq : (sel == 1 ? bk : bv);
  unsigned short* outB = outBase + (size_t)sel * outStride;

  f32x4 acc[4][4];
#pragma unroll
  for (int i = 0; i < 4; i++)
#pragma unroll
    for (int j = 0; j < 4; j++) acc[i][j] = (f32x4){0.f, 0.f, 0.f, 0.f};

  int g1i = t, g2i = t + 256;
  const unsigned short* a1 = A + (size_t)(m0 + (g1i >> 2)) * K + (g1i & 3) * 8;
  const unsigned short* a2 = A + (size_t)(m0 + (g2i >> 2)) * K + (g2i & 3) * 8;
  const unsigned short* b1 = W + (size_t)(n0 + (g1i >> 2)) * K + (g1i & 3) * 8;
  const unsigned short* b2 = W + (size_t)(n0 + (g2i >> 2)) * K + (g2i & 3) * 8;
  unsigned short* la1 = &As[g1i * 8];
  unsigned short* la2 = &As[g2i * 8];
  unsigned short* lb1 = &Bs[g1i * 8];
  unsigned short* lb2 = &Bs[g2i * 8];

  for (int kt = 0; kt < K; kt += 32) {
    async_cp16(a1 + kt, la1);
    async_cp16(a2 + kt, la2);
    async_cp16(b1 + kt, lb1);
    async_cp16(b2 + kt, lb2);
    __syncthreads();
    bf16x8 af[4], bfv[4];
#pragma unroll
    for (int mi = 0; mi < 4; mi++)
      af[mi] = *(const bf16x8*)&As[(wr * 64 + mi * 16 + col) * 32 + quad * 8];
#pragma unroll
    for (int ni = 0; ni < 4; ni++)
      bfv[ni] = *(const bf16x8*)&Bs[(wc * 64 + ni * 16 + col) * 32 + quad * 8];
#pragma unroll
    for (int mi = 0; mi < 4; mi++)
#pragma unroll
      for (int ni = 0; ni < 4; ni++)
        acc[mi][ni] = __builtin_amdgcn_mfma_f32_16x16x32_bf16(af[mi], bfv[ni], acc[mi][ni], 0, 0, 0);
    __syncthreads();
  }

  int mBase = m0 + wr * 64, nBase = n0 + wc * 64;
#pragma unroll
  for (int mi = 0; mi < 4; mi++) {
#pragma unroll
    for (int ni = 0; ni < 4; ni++) {
      int n = nBase + ni * 16 + col;
      float bv = b2f(bias[n]);
      f32x4 v = acc[mi][ni];
#pragma unroll
      for (int r = 0; r < 4; r++) {
        int m = mBase + mi * 16 + quad * 4 + r;
        outB[(size_t)m * 512 + n] = f2b(v[r] + bv);
      }
    }
  }
}

// dst[m][ci*3+tap] = src[m+tap-1][ci] (zero-padded along s within each batch)
__global__ void im2col3_kernel(const unsigned short* __restrict__ src,
                               unsigned short* __restrict__ dst, int C)
{
  int m = blockIdx.x;
  int k = blockIdx.y * blockDim.x + threadIdx.x;  // [0, 3C)
  int ci = k / 3;
  int tap = k - ci * 3;
  int s = m & 511;
  int sp = s + tap - 1;
  unsigned short val = 0;
  if (sp >= 0 && sp < 512) val = src[(size_t)(m + tap - 1) * C + ci];
  dst[(size_t)m * (3 * C) + k] = val;
}

// LayerNorm over D=512; one wave per row; z fp32 -> bf16 out.
__global__ __launch_bounds__(256) void ln_kernel(
    const float* __restrict__ z, const unsigned short* __restrict__ gam,
    const unsigned short* __restrict__ bet, unsigned short* __restrict__ out)
{
  int w = threadIdx.x >> 6, l = threadIdx.x & 63;
  int row = blockIdx.x * 4 + w;
  const float* zr = z + (size_t)row * 512;
  float4 v0 = *(const float4*)(zr + l * 8);
  float4 v1 = *(const float4*)(zr + l * 8 + 4);
  float x[8] = {v0.x, v0.y, v0.z, v0.w, v1.x, v1.y, v1.z, v1.w};
  float s = 0.f;
#pragma unroll
  for (int i = 0; i < 8; i++) s += x[i];
#pragma unroll
  for (int mm = 1; mm < 64; mm <<= 1) s += __shfl_xor(s, mm, 64);
  float mu = s * (1.0f / 512.0f);
  float vs = 0.f;
#pragma unroll
  for (int i = 0; i < 8; i++) { float d = x[i] - mu; vs += d * d; }
#pragma unroll
  for (int mm = 1; mm < 64; mm <<= 1) vs += __shfl_xor(vs, mm, 64);
  float rs = rsqrtf(vs * (1.0f / 512.0f) + 1e-5f);
  struct alignas(16) U8 { unsigned short u[8]; };
  U8 gg = *(const U8*)(gam + l * 8);
  U8 bb = *(const U8*)(bet + l * 8);
  U8 o;
#pragma unroll
  for (int i = 0; i < 8; i++) o.u[i] = f2b((x[i] - mu) * rs * b2f(gg.u[i]) + b2f(bb.u[i]));
  *(U8*)(out + (size_t)row * 512 + l * 8) = o;
}

// Final LN on last token only: 16 rows (b, s=511) -> feat[b][512]
__global__ __launch_bounds__(256) void lnf_kernel(
    const float* __restrict__ z, const unsigned short* __restrict__ gam,
    const unsigned short* __restrict__ bet, unsigned short* __restrict__ feat)
{
  int w = threadIdx.x >> 6, l = threadIdx.x & 63;
  int b = blockIdx.x * 4 + w;
  const float* zr = z + ((size_t)b * 512 + 511) * 512;
  float4 v0 = *(const float4*)(zr + l * 8);
  float4 v1 = *(const float4*)(zr + l * 8 + 4);
  float x[8] = {v0.x, v0.y, v0.z, v0.w, v1.x, v1.y, v1.z, v1.w};
  float s = 0.f;
#pragma unroll
  for (int i = 0; i < 8; i++) s += x[i];
#pragma unroll
  for (int mm = 1; mm < 64; mm <<= 1) s += __shfl_xor(s, mm, 64);
  float mu = s * (1.0f / 512.0f);
  float vs = 0.f;
#pragma unroll
  for (int i = 0; i < 8; i++) { float d = x[i] - mu; vs += d * d; }
#pragma unroll
  for (int mm = 1; mm < 64; mm <<= 1) vs += __shfl_xor(vs, mm, 64);
  float rs = rsqrtf(vs * (1.0f / 512.0f) + 1e-5f);
  struct alignas(16) U8 { unsigned short u[8]; };
  U8 gg = *(const U8*)(gam + l * 8);
  U8 bb = *(const U8*)(bet + l * 8);
  U8 o;
#pragma unroll
  for (int i = 0; i < 8; i++) o.u[i] = f2b((x[i] - mu) * rs * b2f(gg.u[i]) + b2f(bb.u[i]));
  *(U8*)(feat + (size_t)b * 512 + l * 8) = o;
}

// V (b,s,h*64+e) -> VT (b,h,e,s)
__global__ __launch_bounds__(256) void vtrans_kernel(const unsigned short* __restrict__ V,
                                                     unsigned short* __restrict__ VT)
{
  __shared__ unsigned short tile[64][72];
  int s0 = blockIdx.x * 64;
  int bh = blockIdx.y; int b = bh >> 3, h = bh & 7;
  int t = threadIdx.x;
  int rs = t >> 2, c = (t & 3) * 16;
  const unsigned short* src = V + ((size_t)(b * 512 + s0 + rs) * 512 + h * 64 + c);
  *(float4*)&tile[rs][c] = *(const float4*)src;
  *(float4*)&tile[rs][c + 8] = *(const float4*)(src + 8);
  __syncthreads();
  unsigned short* dst = VT + ((size_t)(bh * 64 + rs) * 512 + s0 + c);
  union { unsigned short u[16]; float4 f[2]; } ot;
#pragma unroll
  for (int i = 0; i < 16; i++) ot.u[i] = tile[c + i][rs];
  *(float4*)dst = ot.f[0];
  *(float4*)(dst + 8) = ot.f[1];
}

// Fused masked attention, flash-style. Grid (S/64, B*H).
__global__ __launch_bounds__(256) void attn_kernel(
    const unsigned short* __restrict__ Q, const unsigned short* __restrict__ Kg,
    const unsigned short* __restrict__ VT, unsigned short* __restrict__ O)
{
  __shared__ __align__(16) unsigned short Qs[64 * 64];
  __shared__ __align__(16) unsigned short Ks[64 * 64];
  __shared__ __align__(16) unsigned short Vts[64 * 64];
  __shared__ __align__(16) unsigned short Ps[64 * 64];
  const float NEG = -1e30f;
  int bh = blockIdx.y; int b = bh >> 3, h = bh & 7;
  int i0 = blockIdx.x * 64;
  int t = threadIdx.x, w = t >> 6, l = t & 63;
  int col = l & 15, quad = l >> 4;
  int dil = 1 << (h < 4 ? h : 4);
  int per_m1 = 2 * dil - 1;

  {
    int row = t >> 2, c = (t & 3) * 16;
    const unsigned short* src = Q + ((size_t)(b * 512 + i0 + row) * 512 + h * 64 + c);
    *(float4*)&Qs[row * 64 + c] = *(const float4*)src;
    *(float4*)&Qs[row * 64 + c + 8] = *(const float4*)(src + 8);
  }
  __syncthreads();

  bf16x8 qa[2];
#pragma unroll
  for (int kk = 0; kk < 2; kk++)
    qa[kk] = *(const bf16x8*)&Qs[(w * 16 + col) * 64 + kk * 32 + quad * 8];

  f32x4 acc_o[4];
#pragma unroll
  for (int i = 0; i < 4; i++) acc_o[i] = (f32x4){0.f, 0.f, 0.f, 0.f};
  float m_run[4], l_run[4];
#pragma unroll
  for (int r = 0; r < 4; r++) { m_run[r] = NEG; l_run[r] = 0.f; }

  for (int jt = 0; jt < 8; jt++) {
    int j0 = jt * 64;
    {
      int row = t >> 2, c = (t & 3) * 16;
      const unsigned short* ks = Kg + ((size_t)(b * 512 + j0 + row) * 512 + h * 64 + c);
      *(float4*)&Ks[row * 64 + c] = *(const float4*)ks;
      *(float4*)&Ks[row * 64 + c + 8] = *(const float4*)(ks + 8);
      const unsigned short* vs = VT + ((size_t)(bh * 64 + row) * 512 + j0 + c);
      *(float4*)&Vts[row * 64 + c] = *(const float4*)vs;
      *(float4*)&Vts[row * 64 + c + 8] = *(const float4*)(vs + 8);
    }
    __syncthreads();

    f32x4 sa[4];
#pragma unroll
    for (int ni = 0; ni < 4; ni++) {
      f32x4 s = (f32x4){0.f, 0.f, 0.f, 0.f};
#pragma unroll
      for (int kk = 0; kk < 2; kk++) {
        bf16x8 kb = *(const bf16x8*)&Ks[(ni * 16 + col) * 64 + kk * 32 + quad * 8];
        s = __builtin_amdgcn_mfma_f32_16x16x32_bf16(qa[kk], kb, s, 0, 0, 0);
      }
      sa[ni] = s;
    }

    float pv[4][4];
    float alpha_r[4];
#pragma unroll
    for (int r = 0; r < 4; r++) {
      int ig = i0 + w * 16 + quad * 4 + r;
      float sv[4]; float mx = NEG;
#pragma unroll
      for (int ni = 0; ni < 4; ni++) {
        int jg = j0 + ni * 16 + col;
        int d = ig - jg; d = d < 0 ? -d : d;
        bool keep = (d <= dil) || ((d & per_m1) == 0);
        float s = keep ? fminf(sa[ni][r] * 0.125f, 80.0f) : NEG;
        sv[ni] = s; mx = fmaxf(mx, s);
      }
#pragma unroll
      for (int mm = 1; mm < 16; mm <<= 1) mx = fmaxf(mx, __shfl_xor(mx, mm, 64));
      float mN = fmaxf(m_run[r], mx);
      float a = __expf(m_run[r] - mN);
      float rsum = 0.f;
#pragma unroll
      for (int ni = 0; ni < 4; ni++) { float p = __expf(sv[ni] - mN); pv[ni][r] = p; rsum += p; }
#pragma unroll
      for (int mm = 1; mm < 16; mm <<= 1) rsum += __shfl_xor(rsum, mm, 64);
      l_run[r] = l_run[r] * a + rsum;
      m_run[r] = mN;
      alpha_r[r] = a;
    }
#pragma unroll
    for (int ne = 0; ne < 4; ne++)
#pragma unroll
      for (int r = 0; r < 4; r++) acc_o[ne][r] *= alpha_r[r];
#pragma unroll
    for (int ni = 0; ni < 4; ni++)
#pragma unroll
      for (int r = 0; r < 4; r++)
        Ps[(w * 16 + quad * 4 + r) * 64 + ni * 16 + col] = f2b(pv[ni][r]);
    __syncthreads();

    bf16x8 pa[2];
#pragma unroll
    for (int kk = 0; kk < 2; kk++)
      pa[kk] = *(const bf16x8*)&Ps[(w * 16 + col) * 64 + kk * 32 + quad * 8];
#pragma unroll
    for (int ne = 0; ne < 4; ne++) {
#pragma unroll
      for (int kk = 0; kk < 2; kk++) {
        bf16x8 vb = *(const bf16x8*)&Vts[(ne * 16 + col) * 64 + kk * 32 + quad * 8];
        acc_o[ne] = __builtin_amdgcn_mfma_f32_16x16x32_bf16(pa[kk], vb, acc_o[ne], 0, 0, 0);
      }
    }
    __syncthreads();
  }

  float inv[4];
#pragma unroll
  for (int r = 0; r < 4; r++) inv[r] = 1.0f / fmaxf(l_run[r], 1e-20f);
#pragma unroll
  for (int ne = 0; ne < 4; ne++)
#pragma unroll
    for (int r = 0; r < 4; r++) {
      float o = acc_o[ne][r] * inv[r];
      O[((size_t)(b * 512 + i0 + w * 16 + quad * 4 + r)) * 512 + h * 64 + ne * 16 + col] = f2b(o);
    }
}

// Both MLP heads for one sample per block; output dtype per flag.
__global__ __launch_bounds__(256) void heads_kernel(
    const unsigned short* __restrict__ feat,
    const unsigned short* __restrict__ a1w, const unsigned short* __restrict__ a1b,
    const unsigned short* __restrict__ a2w, const unsigned short* __restrict__ a2b,
    const unsigned short* __restrict__ a3w, const unsigned short* __restrict__ a3b,
    const unsigned short* __restrict__ a4w, const unsigned short* __restrict__ a4b,
    const unsigned short* __restrict__ c1w, const unsigned short* __restrict__ c1b,
    const unsigned short* __restrict__ c2w, const unsigned short* __restrict__ c2b,
    const unsigned short* __restrict__ c3w, const unsigned short* __restrict__ c3b,
    const unsigned short* __restrict__ c4w, const unsigned short* __restrict__ c4b,
    const int* __restrict__ flag, void* __restrict__ outv)
{
  __shared__ float f[512];
  __shared__ float g1[256];
  __shared__ float g2[512];
  __shared__ float g3[128];
  int b = blockIdx.x, t = threadIdx.x;
  f[t] = b2f(feat[b * 512 + t]);
  f[t + 256] = b2f(feat[b * 512 + 256 + t]);
  __syncthreads();
  {
    const unsigned short* wrow; float bias;
    if (t < 128) { wrow = a1w + (size_t)t * 512; bias = b2f(a1b[t]); }
    else { wrow = c1w + (size_t)(t - 128) * 512; bias = b2f(c1b[t - 128]); }
    float s = bias;
    for (int k = 0; k < 512; k++) s += b2f(wrow[k]) * f[k];
    g1[t] = gelu_f(s);
  }
  __syncthreads();
  {
    float s1 = b2f(a2b[t]);
    for (int k = 0; k < 128; k++) s1 += b2f(a2w[t * 128 + k]) * g1[k];
    float s2 = b2f(c2b[t]);
    for (int k = 0; k < 128; k++) s2 += b2f(c2w[t * 128 + k]) * g1[128 + k];
    g2[t] = gelu_f(s1);
    g2[256 + t] = gelu_f(s2);
  }
  __syncthreads();
  if (t < 57) {
    float s = b2f(a3b[t]);
    for (int k = 0; k < 256; k++) s += b2f(a3w[t * 256 + k]) * g2[k];
    g3[t] = gelu_f(s);
  } else if (t >= 64 && t < 121) {
    int u = t - 64;
    float s = b2f(c3b[u]);
    for (int k = 0; k < 256; k++) s += b2f(c3w[u * 256 + k]) * g2[256 + k];
    g3[64 + u] = gelu_f(s);
  }
  __syncthreads();
  int fp32out = *flag;
  if (t < 3) {
    float s = b2f(a4b[t]);
    for (int k = 0; k < 57; k++) s += b2f(a4w[t * 57 + k]) * g3[k];
    if (fp32out) ((float*)outv)[b * 3 + t] = s;
    else ((unsigned short*)outv)[b * 3 + t] = f2b(s);
  } else if (t == 4) {
    float s = b2f(c4b[0]);
    for (int k = 0; k < 57; k++) s += b2f(c4w[k]) * g3[64 + k];
    if (fp32out) ((float*)outv)[48 + b] = s;
    else ((unsigned short*)outv)[48 + b] = f2b(s);
  }
}

extern "C" void kernel_launch(void* const* d_in, const int* in_sizes, int n_in,
                              void* d_out, int out_size, void* d_ws, size_t ws_size,
                              hipStream_t stream)
{
  typedef unsigned short u16;

  // ws layout: z [0,16M) | R [16M,48M) | bufH [48M,56M) | pool [56M,~85M) | flag @88M
  char* ws = (char*)d_ws;
  float* z    = (float*)ws;
  u16* R      = (u16*)(ws + (16u << 20));
  u16* bufQ   = R;
  u16* bufK   = (u16*)(ws + (24u << 20));
  u16* bufV   = (u16*)(ws + (32u << 20));
  u16* bufVT  = (u16*)(ws + (40u << 20));
  u16* bufO   = bufV;
  u16* bufH   = (u16*)(ws + (48u << 20));
  u16* feat   = R;
  u16* pool   = (u16*)(ws + (56u << 20));
  int* flag   = (int*)(ws + (88u << 20));

  // canonicalize inputs -> bf16 pool
  CvtArgs args;
  unsigned int off = 0;
  int nt = n_in < 42 ? n_in : 42;
  for (int i = 0; i < nt; i++) { args.src[i] = d_in[i]; args.off[i] = off; off += (unsigned int)in_sizes[i]; }
  args.off[nt] = off;
  unsigned int total = off;

  probe_kernel<<<1, 64, 0, stream>>>((const unsigned int*)d_in[24], flag);
  cvt_kernel<<<(total + 2047) / 2048, 256, 0, stream>>>(args, nt, total, flag, pool);

  const u16* P[42];
  for (int i = 0; i < nt; i++) P[i] = pool + args.off[i];
  const u16* x       = P[0];
  const u16* conv1_w = P[1];  const u16* conv1_b = P[2];
  const u16* conv2_w = P[3];  const u16* conv2_b = P[4];
  const u16* emb_w   = P[5];  const u16* emb_b   = P[6];
  const u16* pos     = P[7];
  const u16* Wq      = P[8];  const u16* bq      = P[9];
  const u16* Wk      = P[10]; const u16* bk      = P[11];
  const u16* Wv      = P[12]; const u16* bv      = P[13];
  const u16* Wo      = P[14]; const u16* bo      = P[15];
  const u16* ln1_g   = P[16]; const u16* ln1_b   = P[17];
  const u16* ln2_g   = P[18]; const u16* ln2_b   = P[19];
  const u16* W1      = P[20]; const u16* b1      = P[21];
  const u16* W2      = P[22]; const u16* b2      = P[23];
  const u16* lnf_g   = P[24]; const u16* lnf_b   = P[25];

  // conv front-end as im2col + GEMM(+GELU)
  im2col3_kernel<<<dim3(8192, 1), 192, 0, stream>>>(x, R, 64);
  gemm_bt<<<dim3(64, 2), 256, 0, stream>>>(R, conv1_w, conv1_b, bufH, nullptr, nullptr, 256, 192, 1);
  im2col3_kernel<<<dim3(8192, 3), 256, 0, stream>>>(bufH, R, 256);
  gemm_bt<<<dim3(64, 4), 256, 0, stream>>>(R, conv2_w, conv2_b, bufH, nullptr, nullptr, 512, 768, 1);
  gemm_bt<<<dim3(64, 4), 256, 0, stream>>>(bufH, emb_w, emb_b, nullptr, z, pos, 512, 512, 2);

  const size_t qkvStride = (8u << 20) / 2;  // 4M elements between Q,K,V regions
  for (int l = 0; l < 4; l++) {
    ln_kernel<<<2048, 256, 0, stream>>>(z, ln1_g + l * 512, ln1_b + l * 512, bufH);
    gemm_qkv<<<dim3(64, 12), 256, 0, stream>>>(bufH,
        Wq + (size_t)l * 262144, Wk + (size_t)l * 262144, Wv + (size_t)l * 262144,
        bq + l * 512, bk + l * 512, bv + l * 512, bufQ, qkvStride, 512);
    vtrans_kernel<<<dim3(8, 128), 256, 0, stream>>>(bufV, bufVT);
    attn_kernel<<<dim3(8, 128), 256, 0, stream>>>(bufQ, bufK, bufVT, bufO);
    gemm_bt<<<dim3(64, 4), 256, 0, stream>>>(bufO, Wo + (size_t)l * 262144, bo + l * 512, nullptr, z, nullptr, 512, 512, 3);
    ln_kernel<<<2048, 256, 0, stream>>>(z, ln2_g + l * 512, ln2_b + l * 512, bufH);
    gemm_bt<<<dim3(64, 16), 256, 0, stream>>>(bufH, W1 + (size_t)l * 1048576, b1 + l * 2048, R, nullptr, nullptr, 2048, 512, 1);
    gemm_bt<<<dim3(64, 4), 256, 0, stream>>>(R, W2 + (size_t)l * 1048576, b2 + l * 512, nullptr, z, nullptr, 512, 2048, 3);
  }

  lnf_kernel<<<4, 256, 0, stream>>>(z, lnf_g, lnf_b, feat);
  heads_kernel<<<16, 256, 0, stream>>>(feat,
      P[26], P[27], P[28], P[29], P[30], P[31], P[32], P[33],
      P[34], P[35], P[36], P[37], P[38], P[39], P[40], P[41],
      flag, d_out);
}

// Round 6
// 1189.657 us; speedup vs baseline: 1.2565x; 1.0716x over previous
//
#include <hip/hip_runtime.h>
#include <hip/hip_bf16.h>
#include <cstdint>

typedef __attribute__((ext_vector_type(8))) short bf16x8;
typedef __attribute__((ext_vector_type(4))) float f32x4;
typedef unsigned short u16;

#define DEV __device__ __forceinline__

DEV float b2f(u16 u) {
  union { unsigned int i; float f; } v; v.i = ((unsigned int)u) << 16; return v.f;
}
DEV u16 f2b(float f) {
  __hip_bfloat16 h = __float2bfloat16(f);
  return *reinterpret_cast<u16*>(&h);
}
DEV float gelu_f(float x) { return 0.5f * x * (1.0f + erff(x * 0.70710678118654752f)); }

DEV void async_cp16(const u16* g, u16* l) {
  __builtin_amdgcn_global_load_lds(
      (const __attribute__((address_space(1))) void*)g,
      (__attribute__((address_space(3))) void*)l, 16, 0, 0);
}

// ---- dtype canonicalization ------------------------------------------------
__global__ void probe_kernel(const unsigned int* __restrict__ g, int* __restrict__ flag) {
  if (threadIdx.x == 0 && blockIdx.x == 0) *flag = (*g == 0x3F800000u) ? 1 : 0;
}

struct CvtArgs {
  const void* src[42];
  unsigned int off[43];
};

struct alignas(16) U8v { u16 u[8]; };

__global__ __launch_bounds__(256) void cvt_kernel(CvtArgs a, int n_t, unsigned int total,
                                                  const int* __restrict__ flag,
                                                  u16* __restrict__ dst) {
  unsigned int i8 = (blockIdx.x * 256u + threadIdx.x) * 8u;
  if (i8 >= total) return;
  int t = 0;
  while (t + 1 < n_t && i8 >= a.off[t + 1]) t++;
  unsigned int j = i8 - a.off[t];
  bool in_seg = (i8 + 8 <= a.off[t + 1]) && (i8 + 8 <= total);
  int fp32 = *flag;
  if (fp32) {
    if (in_seg && ((j & 3) == 0)) {
      const float* s = (const float*)a.src[t] + j;
      float4 v0 = *(const float4*)s;
      float4 v1 = *(const float4*)(s + 4);
      U8v o;
      o.u[0] = f2b(v0.x); o.u[1] = f2b(v0.y); o.u[2] = f2b(v0.z); o.u[3] = f2b(v0.w);
      o.u[4] = f2b(v1.x); o.u[5] = f2b(v1.y); o.u[6] = f2b(v1.z); o.u[7] = f2b(v1.w);
      *(U8v*)(dst + i8) = o;
    } else {
      for (int k = 0; k < 8; k++) {
        unsigned int i = i8 + k;
        if (i >= total) break;
        int tt = t;
        while (tt + 1 < n_t && i >= a.off[tt + 1]) tt++;
        dst[i] = f2b(((const float*)a.src[tt])[i - a.off[tt]]);
      }
    }
  } else {
    if (in_seg && ((j & 7) == 0)) {
      *(U8v*)(dst + i8) = *(const U8v*)((const u16*)a.src[t] + j);
    } else {
      for (int k = 0; k < 8; k++) {
        unsigned int i = i8 + k;
        if (i >= total) break;
        int tt = t;
        while (tt + 1 < n_t && i >= a.off[tt + 1]) tt++;
        dst[i] = ((const u16*)a.src[tt])[i - a.off[tt]];
      }
    }
  }
}

// ---- wave-private pipelined GEMM core ---------------------------------------
// Each wave computes a 64x64 tile with private double-buffered LDS staging and
// fine-grained vmcnt waits. NO __syncthreads in the K-loop (barrier-free).
// LDS per wave: 2 bufs x (A 64x32 + B 64x32) = 16 KB.
DEV void issue8(const u16* Ab, const u16* Bb, int K, int kt, u16* lA, u16* lB, int l) {
  int r0 = l >> 2, q = l & 3;
  const u16* ga = Ab + (size_t)r0 * K + kt + q * 8;
  const u16* gb = Bb + (size_t)r0 * K + kt + q * 8;
  u16* da = lA + l * 8;
  u16* db = lB + l * 8;
#pragma unroll
  for (int j = 0; j < 4; j++) {
    async_cp16(ga + (size_t)(16 * j) * K, da + j * 512);
    async_cp16(gb + (size_t)(16 * j) * K, db + j * 512);
  }
}

DEV void wave_gemm(const u16* Ab, const u16* Bb, int K, u16* wlds, int l,
                   f32x4 (&acc)[4][4]) {
  int col = l & 15, quad = l >> 4;
  u16* A0 = wlds;
  u16* B0 = wlds + 2048;
  u16* A1 = wlds + 4096;
  u16* B1 = wlds + 6144;
  int nK = K >> 5;
  issue8(Ab, Bb, K, 0, A0, B0, l);
  for (int ki = 0; ki < nK; ki++) {
    const u16* cA = (ki & 1) ? A1 : A0;
    const u16* cB = (ki & 1) ? B1 : B0;
    if (ki + 1 < nK) {
      issue8(Ab, Bb, K, (ki + 1) << 5, (ki & 1) ? A0 : A1, (ki & 1) ? B0 : B1, l);
      __builtin_amdgcn_s_waitcnt(0x0F78);  // vmcnt(8): previous tile landed
    } else {
      __builtin_amdgcn_s_waitcnt(0x0F70);  // vmcnt(0): last tile landed
    }
    __builtin_amdgcn_sched_barrier(0);     // keep ds_reads below the wait
    bf16x8 af[4], bfv[4];
#pragma unroll
    for (int mi = 0; mi < 4; mi++)
      af[mi] = *(const bf16x8*)&cA[(mi * 16 + col) * 32 + quad * 8];
#pragma unroll
    for (int ni = 0; ni < 4; ni++)
      bfv[ni] = *(const bf16x8*)&cB[(ni * 16 + col) * 32 + quad * 8];
#pragma unroll
    for (int mi = 0; mi < 4; mi++)
#pragma unroll
      for (int ni = 0; ni < 4; ni++)
        acc[mi][ni] = __builtin_amdgcn_mfma_f32_16x16x32_bf16(af[mi], bfv[ni], acc[mi][ni], 0, 0, 0);
  }
}

// C = epi(A[M,K] @ W[N,K]^T + bias)
// mode 0: bf16 out = x + bias
// mode 1: bf16 out = gelu(x + bias)
// mode 2: f32  out = x + bias + pos[(m&511)*512+n]
// mode 3: f32  out[m*N+n] += x + bias   (residual accumulate)
__global__ __launch_bounds__(256) void gemm_bt(
    const u16* __restrict__ A, const u16* __restrict__ W,
    const u16* __restrict__ bias,
    u16* __restrict__ outB, float* __restrict__ outF,
    const u16* __restrict__ pos,
    int N, int K, int mode)
{
  __shared__ __align__(16) u16 lds[4][8192];
  int t = threadIdx.x, l = t & 63, w = t >> 6;
  int wr = w >> 1, wc = w & 1;
  int col = l & 15, quad = l >> 4;
  int m0 = blockIdx.x * 128 + wr * 64;
  int n0 = blockIdx.y * 128 + wc * 64;

  f32x4 acc[4][4];
#pragma unroll
  for (int i = 0; i < 4; i++)
#pragma unroll
    for (int j = 0; j < 4; j++) acc[i][j] = (f32x4){0.f, 0.f, 0.f, 0.f};

  wave_gemm(A + (size_t)m0 * K, W + (size_t)n0 * K, K, &lds[w][0], l, acc);

#pragma unroll
  for (int mi = 0; mi < 4; mi++) {
#pragma unroll
    for (int ni = 0; ni < 4; ni++) {
      int n = n0 + ni * 16 + col;
      float bv = b2f(bias[n]);
      f32x4 v = acc[mi][ni];
#pragma unroll
      for (int r = 0; r < 4; r++) {
        int m = m0 + mi * 16 + quad * 4 + r;
        float x = v[r] + bv;
        if (mode == 0) {
          outB[(size_t)m * N + n] = f2b(x);
        } else if (mode == 1) {
          outB[(size_t)m * N + n] = f2b(gelu_f(x));
        } else if (mode == 2) {
          outF[(size_t)m * N + n] = x + b2f(pos[(m & 511) * 512 + n]);
        } else {
          outF[(size_t)m * N + n] += x;
        }
      }
    }
  }
}

// Fused Q,K,V projection. blockIdx.y in [0,12): sel=y>>2 picks {Wq,Wk,Wv}.
__global__ __launch_bounds__(256) void gemm_qkv(
    const u16* __restrict__ A,
    const u16* __restrict__ Wq, const u16* __restrict__ Wk, const u16* __restrict__ Wv,
    const u16* __restrict__ bq, const u16* __restrict__ bk, const u16* __restrict__ bv,
    u16* __restrict__ outBase, size_t outStride, int K)
{
  __shared__ __align__(16) u16 lds[4][8192];
  int t = threadIdx.x, l = t & 63, w = t >> 6;
  int wr = w >> 1, wc = w & 1;
  int col = l & 15, quad = l >> 4;
  int m0 = blockIdx.x * 128 + wr * 64;
  int sel = blockIdx.y >> 2;
  int n0 = (blockIdx.y & 3) * 128 + wc * 64;
  const u16* W = sel == 0 ? Wq : (sel == 1 ? Wk : Wv);
  const u16* bias = sel == 0 ? bq : (sel == 1 ? bk : bv);
  u16* outB = outBase + (size_t)sel * outStride;

  f32x4 acc[4][4];
#pragma unroll
  for (int i = 0; i < 4; i++)
#pragma unroll
    for (int j = 0; j < 4; j++) acc[i][j] = (f32x4){0.f, 0.f, 0.f, 0.f};

  wave_gemm(A + (size_t)m0 * K, W + (size_t)n0 * K, K, &lds[w][0], l, acc);

#pragma unroll
  for (int mi = 0; mi < 4; mi++) {
#pragma unroll
    for (int ni = 0; ni < 4; ni++) {
      int n = n0 + ni * 16 + col;
      float bv = b2f(bias[n]);
      f32x4 v = acc[mi][ni];
#pragma unroll
      for (int r = 0; r < 4; r++) {
        int m = m0 + mi * 16 + quad * 4 + r;
        outB[(size_t)m * 512 + n] = f2b(v[r] + bv);
      }
    }
  }
}

// dst[m][ci*3+tap] = src[m+tap-1][ci] (zero-padded along s within each batch)
__global__ void im2col3_kernel(const u16* __restrict__ src,
                               u16* __restrict__ dst, int C)
{
  int m = blockIdx.x;
  int k = blockIdx.y * blockDim.x + threadIdx.x;
  int ci = k / 3;
  int tap = k - ci * 3;
  int s = m & 511;
  int sp = s + tap - 1;
  u16 val = 0;
  if (sp >= 0 && sp < 512) val = src[(size_t)(m + tap - 1) * C + ci];
  dst[(size_t)m * (3 * C) + k] = val;
}

// LayerNorm over D=512; one wave per row; z fp32 -> bf16 out.
__global__ __launch_bounds__(256) void ln_kernel(
    const float* __restrict__ z, const u16* __restrict__ gam,
    const u16* __restrict__ bet, u16* __restrict__ out)
{
  int w = threadIdx.x >> 6, l = threadIdx.x & 63;
  int row = blockIdx.x * 4 + w;
  const float* zr = z + (size_t)row * 512;
  float4 v0 = *(const float4*)(zr + l * 8);
  float4 v1 = *(const float4*)(zr + l * 8 + 4);
  float x[8] = {v0.x, v0.y, v0.z, v0.w, v1.x, v1.y, v1.z, v1.w};
  float s = 0.f;
#pragma unroll
  for (int i = 0; i < 8; i++) s += x[i];
#pragma unroll
  for (int mm = 1; mm < 64; mm <<= 1) s += __shfl_xor(s, mm, 64);
  float mu = s * (1.0f / 512.0f);
  float vs = 0.f;
#pragma unroll
  for (int i = 0; i < 8; i++) { float d = x[i] - mu; vs += d * d; }
#pragma unroll
  for (int mm = 1; mm < 64; mm <<= 1) vs += __shfl_xor(vs, mm, 64);
  float rs = rsqrtf(vs * (1.0f / 512.0f) + 1e-5f);
  U8v gg = *(const U8v*)(gam + l * 8);
  U8v bb = *(const U8v*)(bet + l * 8);
  U8v o;
#pragma unroll
  for (int i = 0; i < 8; i++) o.u[i] = f2b((x[i] - mu) * rs * b2f(gg.u[i]) + b2f(bb.u[i]));
  *(U8v*)(out + (size_t)row * 512 + l * 8) = o;
}

// Final LN on last token only: 16 rows (b, s=511) -> feat[b][512]
__global__ __launch_bounds__(256) void lnf_kernel(
    const float* __restrict__ z, const u16* __restrict__ gam,
    const u16* __restrict__ bet, u16* __restrict__ feat)
{
  int w = threadIdx.x >> 6, l = threadIdx.x & 63;
  int b = blockIdx.x * 4 + w;
  const float* zr = z + ((size_t)b * 512 + 511) * 512;
  float4 v0 = *(const float4*)(zr + l * 8);
  float4 v1 = *(const float4*)(zr + l * 8 + 4);
  float x[8] = {v0.x, v0.y, v0.z, v0.w, v1.x, v1.y, v1.z, v1.w};
  float s = 0.f;
#pragma unroll
  for (int i = 0; i < 8; i++) s += x[i];
#pragma unroll
  for (int mm = 1; mm < 64; mm <<= 1) s += __shfl_xor(s, mm, 64);
  float mu = s * (1.0f / 512.0f);
  float vs = 0.f;
#pragma unroll
  for (int i = 0; i < 8; i++) { float d = x[i] - mu; vs += d * d; }
#pragma unroll
  for (int mm = 1; mm < 64; mm <<= 1) vs += __shfl_xor(vs, mm, 64);
  float rs = rsqrtf(vs * (1.0f / 512.0f) + 1e-5f);
  U8v gg = *(const U8v*)(gam + l * 8);
  U8v bb = *(const U8v*)(bet + l * 8);
  U8v o;
#pragma unroll
  for (int i = 0; i < 8; i++) o.u[i] = f2b((x[i] - mu) * rs * b2f(gg.u[i]) + b2f(bb.u[i]));
  *(U8v*)(feat + (size_t)b * 512 + l * 8) = o;
}

// V (b,s,h*64+e) -> VT (b,h,e,s)
__global__ __launch_bounds__(256) void vtrans_kernel(const u16* __restrict__ V,
                                                     u16* __restrict__ VT)
{
  __shared__ u16 tile[64][72];
  int s0 = blockIdx.x * 64;
  int bh = blockIdx.y; int b = bh >> 3, h = bh & 7;
  int t = threadIdx.x;
  int rs = t >> 2, c = (t & 3) * 16;
  const u16* src = V + ((size_t)(b * 512 + s0 + rs) * 512 + h * 64 + c);
  *(float4*)&tile[rs][c] = *(const float4*)src;
  *(float4*)&tile[rs][c + 8] = *(const float4*)(src + 8);
  __syncthreads();
  u16* dst = VT + ((size_t)(bh * 64 + rs) * 512 + s0 + c);
  union { u16 u[16]; float4 f[2]; } ot;
#pragma unroll
  for (int i = 0; i < 16; i++) ot.u[i] = tile[c + i][rs];
  *(float4*)dst = ot.f[0];
  *(float4*)(dst + 8) = ot.f[1];
}

// Fused masked attention, flash-style. Grid (S/64, B*H).
__global__ __launch_bounds__(256) void attn_kernel(
    const u16* __restrict__ Q, const u16* __restrict__ Kg,
    const u16* __restrict__ VT, u16* __restrict__ O)
{
  __shared__ __align__(16) u16 Qs[64 * 64];
  __shared__ __align__(16) u16 Ks[64 * 64];
  __shared__ __align__(16) u16 Vts[64 * 64];
  __shared__ __align__(16) u16 Ps[64 * 64];
  const float NEG = -1e30f;
  int bh = blockIdx.y; int b = bh >> 3, h = bh & 7;
  int i0 = blockIdx.x * 64;
  int t = threadIdx.x, w = t >> 6, l = t & 63;
  int col = l & 15, quad = l >> 4;
  int dil = 1 << (h < 4 ? h : 4);
  int per_m1 = 2 * dil - 1;

  {
    int row = t >> 2, c = (t & 3) * 16;
    const u16* src = Q + ((size_t)(b * 512 + i0 + row) * 512 + h * 64 + c);
    *(float4*)&Qs[row * 64 + c] = *(const float4*)src;
    *(float4*)&Qs[row * 64 + c + 8] = *(const float4*)(src + 8);
  }
  __syncthreads();

  bf16x8 qa[2];
#pragma unroll
  for (int kk = 0; kk < 2; kk++)
    qa[kk] = *(const bf16x8*)&Qs[(w * 16 + col) * 64 + kk * 32 + quad * 8];

  f32x4 acc_o[4];
#pragma unroll
  for (int i = 0; i < 4; i++) acc_o[i] = (f32x4){0.f, 0.f, 0.f, 0.f};
  float m_run[4], l_run[4];
#pragma unroll
  for (int r = 0; r < 4; r++) { m_run[r] = NEG; l_run[r] = 0.f; }

  for (int jt = 0; jt < 8; jt++) {
    int j0 = jt * 64;
    {
      int row = t >> 2, c = (t & 3) * 16;
      const u16* ks = Kg + ((size_t)(b * 512 + j0 + row) * 512 + h * 64 + c);
      *(float4*)&Ks[row * 64 + c] = *(const float4*)ks;
      *(float4*)&Ks[row * 64 + c + 8] = *(const float4*)(ks + 8);
      const u16* vs = VT + ((size_t)(bh * 64 + row) * 512 + j0 + c);
      *(float4*)&Vts[row * 64 + c] = *(const float4*)vs;
      *(float4*)&Vts[row * 64 + c + 8] = *(const float4*)(vs + 8);
    }
    __syncthreads();

    f32x4 sa[4];
#pragma unroll
    for (int ni = 0; ni < 4; ni++) {
      f32x4 s = (f32x4){0.f, 0.f, 0.f, 0.f};
#pragma unroll
      for (int kk = 0; kk < 2; kk++) {
        bf16x8 kb = *(const bf16x8*)&Ks[(ni * 16 + col) * 64 + kk * 32 + quad * 8];
        s = __builtin_amdgcn_mfma_f32_16x16x32_bf16(qa[kk], kb, s, 0, 0, 0);
      }
      sa[ni] = s;
    }

    float pv[4][4];
    float alpha_r[4];
#pragma unroll
    for (int r = 0; r < 4; r++) {
      int ig = i0 + w * 16 + quad * 4 + r;
      float sv[4]; float mx = NEG;
#pragma unroll
      for (int ni = 0; ni < 4; ni++) {
        int jg = j0 + ni * 16 + col;
        int d = ig - jg; d = d < 0 ? -d : d;
        bool keep = (d <= dil) || ((d & per_m1) == 0);
        float s = keep ? fminf(sa[ni][r] * 0.125f, 80.0f) : NEG;
        sv[ni] = s; mx = fmaxf(mx, s);
      }
#pragma unroll
      for (int mm = 1; mm < 16; mm <<= 1) mx = fmaxf(mx, __shfl_xor(mx, mm, 64));
      float mN = fmaxf(m_run[r], mx);
      float a = __expf(m_run[r] - mN);
      float rsum = 0.f;
#pragma unroll
      for (int ni = 0; ni < 4; ni++) { float p = __expf(sv[ni] - mN); pv[ni][r] = p; rsum += p; }
#pragma unroll
      for (int mm = 1; mm < 16; mm <<= 1) rsum += __shfl_xor(rsum, mm, 64);
      l_run[r] = l_run[r] * a + rsum;
      m_run[r] = mN;
      alpha_r[r] = a;
    }
#pragma unroll
    for (int ne = 0; ne < 4; ne++)
#pragma unroll
      for (int r = 0; r < 4; r++) acc_o[ne][r] *= alpha_r[r];
#pragma unroll
    for (int ni = 0; ni < 4; ni++)
#pragma unroll
      for (int r = 0; r < 4; r++)
        Ps[(w * 16 + quad * 4 + r) * 64 + ni * 16 + col] = f2b(pv[ni][r]);
    __syncthreads();

    bf16x8 pa[2];
#pragma unroll
    for (int kk = 0; kk < 2; kk++)
      pa[kk] = *(const bf16x8*)&Ps[(w * 16 + col) * 64 + kk * 32 + quad * 8];
#pragma unroll
    for (int ne = 0; ne < 4; ne++) {
#pragma unroll
      for (int kk = 0; kk < 2; kk++) {
        bf16x8 vb = *(const bf16x8*)&Vts[(ne * 16 + col) * 64 + kk * 32 + quad * 8];
        acc_o[ne] = __builtin_amdgcn_mfma_f32_16x16x32_bf16(pa[kk], vb, acc_o[ne], 0, 0, 0);
      }
    }
    __syncthreads();
  }

  float inv[4];
#pragma unroll
  for (int r = 0; r < 4; r++) inv[r] = 1.0f / fmaxf(l_run[r], 1e-20f);
#pragma unroll
  for (int ne = 0; ne < 4; ne++)
#pragma unroll
    for (int r = 0; r < 4; r++) {
      float o = acc_o[ne][r] * inv[r];
      O[((size_t)(b * 512 + i0 + w * 16 + quad * 4 + r)) * 512 + h * 64 + ne * 16 + col] = f2b(o);
    }
}

// Both MLP heads for one sample per block; output dtype per flag.
__global__ __launch_bounds__(256) void heads_kernel(
    const u16* __restrict__ feat,
    const u16* __restrict__ a1w, const u16* __restrict__ a1b,
    const u16* __restrict__ a2w, const u16* __restrict__ a2b,
    const u16* __restrict__ a3w, const u16* __restrict__ a3b,
    const u16* __restrict__ a4w, const u16* __restrict__ a4b,
    const u16* __restrict__ c1w, const u16* __restrict__ c1b,
    const u16* __restrict__ c2w, const u16* __restrict__ c2b,
    const u16* __restrict__ c3w, const u16* __restrict__ c3b,
    const u16* __restrict__ c4w, const u16* __restrict__ c4b,
    const int* __restrict__ flag, void* __restrict__ outv)
{
  __shared__ float f[512];
  __shared__ float g1[256];
  __shared__ float g2[512];
  __shared__ float g3[128];
  int b = blockIdx.x, t = threadIdx.x;
  f[t] = b2f(feat[b * 512 + t]);
  f[t + 256] = b2f(feat[b * 512 + 256 + t]);
  __syncthreads();
  {
    const u16* wrow; float bias;
    if (t < 128) { wrow = a1w + (size_t)t * 512; bias = b2f(a1b[t]); }
    else { wrow = c1w + (size_t)(t - 128) * 512; bias = b2f(c1b[t - 128]); }
    float s = bias;
    for (int k = 0; k < 512; k++) s += b2f(wrow[k]) * f[k];
    g1[t] = gelu_f(s);
  }
  __syncthreads();
  {
    float s1 = b2f(a2b[t]);
    for (int k = 0; k < 128; k++) s1 += b2f(a2w[t * 128 + k]) * g1[k];
    float s2 = b2f(c2b[t]);
    for (int k = 0; k < 128; k++) s2 += b2f(c2w[t * 128 + k]) * g1[128 + k];
    g2[t] = gelu_f(s1);
    g2[256 + t] = gelu_f(s2);
  }
  __syncthreads();
  if (t < 57) {
    float s = b2f(a3b[t]);
    for (int k = 0; k < 256; k++) s += b2f(a3w[t * 256 + k]) * g2[k];
    g3[t] = gelu_f(s);
  } else if (t >= 64 && t < 121) {
    int u = t - 64;
    float s = b2f(c3b[u]);
    for (int k = 0; k < 256; k++) s += b2f(c3w[u * 256 + k]) * g2[256 + k];
    g3[64 + u] = gelu_f(s);
  }
  __syncthreads();
  int fp32out = *flag;
  if (t < 3) {
    float s = b2f(a4b[t]);
    for (int k = 0; k < 57; k++) s += b2f(a4w[t * 57 + k]) * g3[k];
    if (fp32out) ((float*)outv)[b * 3 + t] = s;
    else ((u16*)outv)[b * 3 + t] = f2b(s);
  } else if (t == 4) {
    float s = b2f(c4b[0]);
    for (int k = 0; k < 57; k++) s += b2f(c4w[k]) * g3[64 + k];
    if (fp32out) ((float*)outv)[48 + b] = s;
    else ((u16*)outv)[48 + b] = f2b(s);
  }
}

extern "C" void kernel_launch(void* const* d_in, const int* in_sizes, int n_in,
                              void* d_out, int out_size, void* d_ws, size_t ws_size,
                              hipStream_t stream)
{
  // ws layout: z [0,16M) | R [16M,48M) | bufH [48M,56M) | pool [56M,~85M) | flag @88M
  char* ws = (char*)d_ws;
  float* z    = (float*)ws;
  u16* R      = (u16*)(ws + (16u << 20));
  u16* bufQ   = R;
  u16* bufK   = (u16*)(ws + (24u << 20));
  u16* bufV   = (u16*)(ws + (32u << 20));
  u16* bufVT  = (u16*)(ws + (40u << 20));
  u16* bufO   = bufV;
  u16* bufH   = (u16*)(ws + (48u << 20));
  u16* feat   = R;
  u16* pool   = (u16*)(ws + (56u << 20));
  int* flag   = (int*)(ws + (88u << 20));

  CvtArgs args;
  unsigned int off = 0;
  int nt = n_in < 42 ? n_in : 42;
  for (int i = 0; i < nt; i++) { args.src[i] = d_in[i]; args.off[i] = off; off += (unsigned int)in_sizes[i]; }
  args.off[nt] = off;
  unsigned int total = off;

  probe_kernel<<<1, 64, 0, stream>>>((const unsigned int*)d_in[24], flag);
  cvt_kernel<<<(total + 2047) / 2048, 256, 0, stream>>>(args, nt, total, flag, pool);

  const u16* P[42];
  for (int i = 0; i < nt; i++) P[i] = pool + args.off[i];
  const u16* x       = P[0];
  const u16* conv1_w = P[1];  const u16* conv1_b = P[2];
  const u16* conv2_w = P[3];  const u16* conv2_b = P[4];
  const u16* emb_w   = P[5];  const u16* emb_b   = P[6];
  const u16* pos     = P[7];
  const u16* Wq      = P[8];  const u16* bq      = P[9];
  const u16* Wk      = P[10]; const u16* bk      = P[11];
  const u16* Wv      = P[12]; const u16* bv      = P[13];
  const u16* Wo      = P[14]; const u16* bo      = P[15];
  const u16* ln1_g   = P[16]; const u16* ln1_b   = P[17];
  const u16* ln2_g   = P[18]; const u16* ln2_b   = P[19];
  const u16* W1      = P[20]; const u16* b1      = P[21];
  const u16* W2      = P[22]; const u16* b2      = P[23];
  const u16* lnf_g   = P[24]; const u16* lnf_b   = P[25];

  im2col3_kernel<<<dim3(8192, 1), 192, 0, stream>>>(x, R, 64);
  gemm_bt<<<dim3(64, 2), 256, 0, stream>>>(R, conv1_w, conv1_b, bufH, nullptr, nullptr, 256, 192, 1);
  im2col3_kernel<<<dim3(8192, 3), 256, 0, stream>>>(bufH, R, 256);
  gemm_bt<<<dim3(64, 4), 256, 0, stream>>>(R, conv2_w, conv2_b, bufH, nullptr, nullptr, 512, 768, 1);
  gemm_bt<<<dim3(64, 4), 256, 0, stream>>>(bufH, emb_w, emb_b, nullptr, z, pos, 512, 512, 2);

  const size_t qkvStride = (8u << 20) / 2;
  for (int l = 0; l < 4; l++) {
    ln_kernel<<<2048, 256, 0, stream>>>(z, ln1_g + l * 512, ln1_b + l * 512, bufH);
    gemm_qkv<<<dim3(64, 12), 256, 0, stream>>>(bufH,
        Wq + (size_t)l * 262144, Wk + (size_t)l * 262144, Wv + (size_t)l * 262144,
        bq + l * 512, bk + l * 512, bv + l * 512, bufQ, qkvStride, 512);
    vtrans_kernel<<<dim3(8, 128), 256, 0, stream>>>(bufV, bufVT);
    attn_kernel<<<dim3(8, 128), 256, 0, stream>>>(bufQ, bufK, bufVT, bufO);
    gemm_bt<<<dim3(64, 4), 256, 0, stream>>>(bufO, Wo + (size_t)l * 262144, bo + l * 512, nullptr, z, nullptr, 512, 512, 3);
    ln_kernel<<<2048, 256, 0, stream>>>(z, ln2_g + l * 512, ln2_b + l * 512, bufH);
    gemm_bt<<<dim3(64, 16), 256, 0, stream>>>(bufH, W1 + (size_t)l * 1048576, b1 + l * 2048, R, nullptr, nullptr, 2048, 512, 1);
    gemm_bt<<<dim3(64, 4), 256, 0, stream>>>(R, W2 + (size_t)l * 1048576, b2 + l * 512, nullptr, z, nullptr, 512, 2048, 3);
  }

  lnf_kernel<<<4, 256, 0, stream>>>(z, lnf_g, lnf_b, feat);
  heads_kernel<<<16, 256, 0, stream>>>(feat,
      P[26], P[27], P[28], P[29], P[30], P[31], P[32], P[33],
      P[34], P[35], P[36], P[37], P[38], P[39], P[40], P[41],
      flag, d_out);
}